// Round 1
// baseline (7817.916 us; speedup 1.0000x reference)
//
#include <hip/hip_runtime.h>

// B=256, D=128, T=512, E=128, H=512, WH=512, WIN=64
typedef __attribute__((ext_vector_type(8))) short s8v;
typedef __attribute__((ext_vector_type(4))) float f4v;

#define MFMA16(a, b, c) __builtin_amdgcn_mfma_f32_16x16x32_bf16((a), (b), (c), 0, 0, 0)

__device__ __forceinline__ unsigned short f2bf(float f) {
  unsigned u = __float_as_uint(f);
  return (unsigned short)((u + 0x7fffu + ((u >> 16) & 1u)) >> 16);
}

// ---------- fp32 -> bf16 conversion (vectorized by 4) ----------
__global__ void cvt4_kernel(const float* __restrict__ in, unsigned short* __restrict__ out, int n4) {
  int i = blockIdx.x * blockDim.x + threadIdx.x;
  if (i >= n4) return;
  float4 v = ((const float4*)in)[i];
  ushort4 o;
  o.x = f2bf(v.x); o.y = f2bf(v.y); o.z = f2bf(v.z); o.w = f2bf(v.w);
  ((ushort4*)out)[i] = o;
}

// ---------- slow_input = [context | e] as bf16 (256 x 640) ----------
__global__ void build_slow_kernel(const float* __restrict__ context, const float* __restrict__ e,
                                  unsigned short* __restrict__ out) {
  int i = blockIdx.x * blockDim.x + threadIdx.x;
  if (i >= 256 * 640) return;
  int b = i / 640, c = i - b * 640;
  float v = (c < 512) ? context[b * 512 + c] : e[b * 128 + (c - 512)];
  out[i] = f2bf(v);
}

// ---------- generic GEMM: C[M][N] = act(A[M][K] @ B[N][K]^T + bias), bf16 in fp32 out ----------
template <int RELU>
__global__ __launch_bounds__(256) void gemm_bt(const unsigned short* __restrict__ A,
                                               const unsigned short* __restrict__ B,
                                               const float* __restrict__ bias, float* __restrict__ C,
                                               int M, int N, int K) {
  __shared__ unsigned short As[64][48];
  __shared__ unsigned short Bs[64][48];
  int tid = threadIdx.x;
  int lane = tid & 63, w = tid >> 6;
  int m = lane & 15, q = lane >> 4;
  int row0 = blockIdx.x * 64, col0 = blockIdx.y * 64;
  int sr = tid >> 2, sk = (tid & 3) * 8;
  const unsigned short* Ap = A + (size_t)(row0 + sr) * K + sk;
  const unsigned short* Bp = B + (size_t)(col0 + sr) * K + sk;
  f4v acc[4];
#pragma unroll
  for (int nt = 0; nt < 4; nt++) acc[nt] = (f4v){0.f, 0.f, 0.f, 0.f};

  for (int k0 = 0; k0 < K; k0 += 32) {
    *(uint4*)&As[sr][sk] = *(const uint4*)(Ap + k0);
    *(uint4*)&Bs[sr][sk] = *(const uint4*)(Bp + k0);
    __syncthreads();
    s8v a = *(const s8v*)&As[w * 16 + m][q * 8];
#pragma unroll
    for (int nt = 0; nt < 4; nt++) {
      s8v bb = *(const s8v*)&Bs[nt * 16 + m][q * 8];
      acc[nt] = MFMA16(a, bb, acc[nt]);
    }
    __syncthreads();
  }
#pragma unroll
  for (int nt = 0; nt < 4; nt++) {
    int c = col0 + nt * 16 + m;
    float bv = bias[c];
#pragma unroll
    for (int i = 0; i < 4; i++) {
      int r = row0 + w * 16 + q * 4 + i;
      float v = acc[nt][i] + bv;
      if (RELU) v = v > 0.f ? v : 0.f;
      C[(size_t)r * N + c] = v;
    }
  }
}

// ---------- phase C: distributed GRU scan ----------
// 512 WGs x 64 threads = 16 batch-groups (16 rows) x 32 col-groups (16 h-cols).
// W_hh slice (48 rows x 512) LDS-resident as MFMA A-fragments. h exchanged via Hall
// (agent-scope L3 ops).
// Sync v2: per-cg VALUE FLAGS instead of per-t counter RMW.
//   flags[bg][cg] (u32) holds the number of completed steps for that cg.
//   Writer: release-fence then store t+1.  Reader: lane l polls flags[bg][l&31],
//   ballot(v >= t) == all.  Pure loads on the poll path -> no RMW serialization,
//   no t/t-1 false sharing (old layout had polled word + RMW word in one 128B line).
// Hall layout: [b][t][h=512] bf16 -> 128 u64 per (b,t).
__global__ __launch_bounds__(64) void gru_scan2(const float* __restrict__ gi,
                                                const unsigned short* __restrict__ Whh,
                                                const float* __restrict__ bhh,
                                                unsigned long long* __restrict__ Hall8,
                                                unsigned int* __restrict__ flags) {
  __shared__ unsigned short wlds[3 * 16 * 64 * 8];  // 48 KB: [g][kc][lane][8]
  int tid = threadIdx.x;
  int bid = blockIdx.x;
  int bg = bid >> 5, cg = bid & 31;
  int b0 = bg * 16;
  int n = tid & 15, q = tid >> 4;

  // stage W slice into LDS in A-fragment order (one-time, 48 KB)
#pragma unroll 1
  for (int it = 0; it < 48; ++it) {
    int g = it >> 4, kc = it & 15;
    int row = g * 512 + cg * 16 + n;
    int kcol = kc * 32 + q * 8;
    *(uint4*)&wlds[(it * 64 + tid) * 8] = *(const uint4*)(Whh + (size_t)row * 512 + kcol);
  }

  // time-invariant gate inputs (gi includes b_ih; fold b_hh for r,z; keep n-gate separate)
  float gir[4], giz[4], gin[4], bhn[4];
#pragma unroll
  for (int i = 0; i < 4; ++i) {
    int c = cg * 16 + q * 4 + i;
    const float* gp = gi + (size_t)(b0 + n) * 1536 + c;
    gir[i] = gp[0] + bhh[c];
    giz[i] = gp[512] + bhh[c + 512];
    gin[i] = gp[1024];
    bhn[i] = bhh[c + 1024];
  }
  float hp[4] = {0.f, 0.f, 0.f, 0.f};
  __syncthreads();

  unsigned int* myflags = flags + bg * 32;
  const unsigned int* pollp = myflags + (tid & 31);
  size_t rowbase = (size_t)(b0 + n) * 512 * 128;     // 128 u64 per (b,t)
  size_t stoff = (size_t)cg * 4 + q;                 // (cg*16+q*4)/4

#pragma unroll 1
  for (int t = 0; t < 512; ++t) {
    f4v ar = {gir[0], gir[1], gir[2], gir[3]};
    f4v az = {giz[0], giz[1], giz[2], giz[3]};
    f4v an = {bhn[0], bhn[1], bhn[2], bhn[3]};
    if (t > 0) {
      // wait for all 32 col-groups to have completed step t-1
      // (bounded loop turns deadlock into wrong answer instead of hang)
      unsigned int tgt = (unsigned int)t;
      for (long sp = 0; sp < 500000L; ++sp) {
        unsigned int v = __hip_atomic_load(pollp, __ATOMIC_RELAXED, __HIP_MEMORY_SCOPE_AGENT);
        if (__ballot(v >= tgt) == 0xffffffffffffffffULL) break;
      }
      __builtin_amdgcn_fence(__ATOMIC_ACQUIRE, "agent");
      unsigned long long* hp8 = Hall8 + rowbase + (size_t)(t - 1) * 128 + q * 2;
      s8v bf[16];
#pragma unroll
      for (int kc = 0; kc < 16; ++kc) {
        union { unsigned long long u[2]; s8v v; } uv;
        uv.u[0] = __hip_atomic_load(hp8 + kc * 8, __ATOMIC_RELAXED, __HIP_MEMORY_SCOPE_AGENT);
        uv.u[1] = __hip_atomic_load(hp8 + kc * 8 + 1, __ATOMIC_RELAXED, __HIP_MEMORY_SCOPE_AGENT);
        bf[kc] = uv.v;
      }
#pragma unroll
      for (int kc = 0; kc < 16; ++kc) {
        s8v a0 = *(const s8v*)&wlds[((0 * 16 + kc) * 64 + tid) * 8];
        ar = MFMA16(a0, bf[kc], ar);
        s8v a1 = *(const s8v*)&wlds[((1 * 16 + kc) * 64 + tid) * 8];
        az = MFMA16(a1, bf[kc], az);
        s8v a2 = *(const s8v*)&wlds[((2 * 16 + kc) * 64 + tid) * 8];
        an = MFMA16(a2, bf[kc], an);
      }
    }
    union { unsigned short s[4]; unsigned long long u; } pk;
#pragma unroll
    for (int i = 0; i < 4; ++i) {
      float r = 1.f / (1.f + __expf(-ar[i]));
      float zg = 1.f / (1.f + __expf(-az[i]));
      float x = gin[i] + r * an[i];
      float ex = __expf(2.f * x);
      float nn = 1.f - 2.f / (ex + 1.f);
      float h = (1.f - zg) * nn + zg * hp[i];
      hp[i] = h;
      pk.s[i] = f2bf(h);
    }
    __hip_atomic_store(Hall8 + rowbase + (size_t)t * 128 + stoff, pk.u,
                       __ATOMIC_RELAXED, __HIP_MEMORY_SCOPE_AGENT);
    // publish: wave-wide release fence (covers all 64 lanes' stores via vmcnt),
    // then one plain flag store (no RMW)
    __builtin_amdgcn_fence(__ATOMIC_RELEASE, "agent");
    if (tid == 0)
      __hip_atomic_store(myflags + cg, (unsigned int)(t + 1),
                         __ATOMIC_RELAXED, __HIP_MEMORY_SCOPE_AGENT);
  }
}

// ---------- phase D+E fused: inc = Hall @ Wfc^T + bfc; out[b,d,t] = zp0 + cumsum_t(inc) ----------
__global__ __launch_bounds__(256) void fc_scan(const unsigned short* __restrict__ Hall,
                                               const unsigned short* __restrict__ Wfc,
                                               const float* __restrict__ bfc,
                                               const float* __restrict__ zctx,
                                               float* __restrict__ out) {
  __shared__ unsigned short hs[16][520];
  int tid = threadIdx.x;
  int lane = tid & 63, w = tid >> 6;
  int m = lane & 15, q = lane >> 4;
  int b = blockIdx.x;

  s8v wf[2][16];
  float bf_r[2], carry[2];
#pragma unroll
  for (int j = 0; j < 2; j++) {
    int d = (2 * w + j) * 16 + m;
#pragma unroll
    for (int kc = 0; kc < 16; kc++)
      wf[j][kc] = *(const s8v*)(Wfc + (size_t)d * 512 + kc * 32 + q * 8);
    bf_r[j] = bfc[d];
    carry[j] = zctx[((size_t)b * 128 + d) * 64 + 63];
  }

#pragma unroll 1
  for (int chunk = 0; chunk < 32; chunk++) {
    int t0 = chunk * 16;
    {
      int mm = tid >> 4, ci = (tid & 15) * 4;
      const unsigned short* src = Hall + ((size_t)b * 512 + t0 + mm) * 512 + ci * 8;
#pragma unroll
      for (int o = 0; o < 4; o++) {
        uint4 v = *(const uint4*)(src + o * 8);
        *(uint4*)&hs[mm][(ci + o) * 8] = v;
      }
    }
    __syncthreads();
    s8v af[16];
#pragma unroll
    for (int kc = 0; kc < 16; kc++) af[kc] = *(const s8v*)&hs[m][kc * 32 + q * 8];
    f4v acc[2];
    acc[0] = (f4v){0.f, 0.f, 0.f, 0.f};
    acc[1] = (f4v){0.f, 0.f, 0.f, 0.f};
#pragma unroll
    for (int kc = 0; kc < 16; kc++) {
      acc[0] = MFMA16(af[kc], wf[0][kc], acc[0]);
      acc[1] = MFMA16(af[kc], wf[1][kc], acc[1]);
    }
    __syncthreads();

#pragma unroll
    for (int j = 0; j < 2; j++) {
      float s0 = acc[j][0] + bf_r[j];
      float s1 = s0 + acc[j][1] + bf_r[j];
      float s2 = s1 + acc[j][2] + bf_r[j];
      float s3 = s2 + acc[j][3] + bf_r[j];
      float tot = s3;
      float incl = tot;
      float u = __shfl_up(incl, 16, 64);
      if (q >= 1) incl += u;
      u = __shfl_up(incl, 32, 64);
      if (q >= 2) incl += u;
      float excl = incl - tot;
      float add = excl + carry[j];
      int d = (2 * w + j) * 16 + m;
      float4 o4 = make_float4(s0 + add, s1 + add, s2 + add, s3 + add);
      *(float4*)(out + ((size_t)b * 128 + d) * 512 + t0 + q * 4) = o4;
      float chunktot = __shfl(incl, 48 + m, 64);
      carry[j] += chunktot;
    }
  }
}

extern "C" void kernel_launch(void* const* d_in, const int* in_sizes, int n_in,
                              void* d_out, int out_size, void* d_ws, size_t ws_size,
                              hipStream_t stream) {
  const float* z_ctx = (const float*)d_in[0];
  const float* e     = (const float*)d_in[4];
  const float* W_enc = (const float*)d_in[5];
  const float* b_enc = (const float*)d_in[6];
  const float* W_ih  = (const float*)d_in[7];
  const float* W_hh  = (const float*)d_in[8];
  const float* b_ih  = (const float*)d_in[9];
  const float* b_hh  = (const float*)d_in[10];
  const float* W_fc  = (const float*)d_in[11];
  const float* b_fc  = (const float*)d_in[12];
  float* out = (float*)d_out;

  char* ws = (char*)d_ws;
  const size_t OFF_WENC = 0;          // 512*8192*2
  const size_t OFF_ZCTX = 8388608;    // 256*8192*2
  const size_t OFF_WIH  = 12582912;   // 1536*640*2
  const size_t OFF_WHH  = 14548992;   // 1536*512*2
  const size_t OFF_WFC  = 16121856;   // 128*512*2
  const size_t OFF_CTX  = 16252928;   // 256*512*4
  const size_t OFF_SLOW = 16777216;   // 256*640*2
  const size_t OFF_GI   = 17104896;   // 256*1536*4
  const size_t OFF_HALL = 18677760;   // 256*512*512*2
  const size_t OFF_CNT  = OFF_HALL + 134217728ull;  // flags: 16*32*4 = 2048 (32KB reserved)
  const size_t NEED = OFF_CNT + 32768;
  if (ws_size < NEED) return;

  unsigned short* Wenc_bf = (unsigned short*)(ws + OFF_WENC);
  unsigned short* zctx_bf = (unsigned short*)(ws + OFF_ZCTX);
  unsigned short* Wih_bf  = (unsigned short*)(ws + OFF_WIH);
  unsigned short* Whh_bf  = (unsigned short*)(ws + OFF_WHH);
  unsigned short* Wfc_bf  = (unsigned short*)(ws + OFF_WFC);
  float* context          = (float*)(ws + OFF_CTX);
  unsigned short* slow_bf = (unsigned short*)(ws + OFF_SLOW);
  float* gi               = (float*)(ws + OFF_GI);
  unsigned short* Hall    = (unsigned short*)(ws + OFF_HALL);
  unsigned long long* Hall8 = (unsigned long long*)(ws + OFF_HALL);
  unsigned int* flags     = (unsigned int*)(ws + OFF_CNT);

  hipMemsetAsync(flags, 0, 4096, stream);

  cvt4_kernel<<<4096, 256, 0, stream>>>(W_enc, Wenc_bf, 512 * 8192 / 4);
  cvt4_kernel<<<2048, 256, 0, stream>>>(z_ctx, zctx_bf, 256 * 8192 / 4);
  cvt4_kernel<<<960, 256, 0, stream>>>(W_ih, Wih_bf, 1536 * 640 / 4);
  cvt4_kernel<<<768, 256, 0, stream>>>(W_hh, Whh_bf, 1536 * 512 / 4);
  cvt4_kernel<<<64, 256, 0, stream>>>(W_fc, Wfc_bf, 128 * 512 / 4);

  gemm_bt<1><<<dim3(4, 8), 256, 0, stream>>>(zctx_bf, Wenc_bf, b_enc, context, 256, 512, 8192);
  build_slow_kernel<<<640, 256, 0, stream>>>(context, e, slow_bf);
  gemm_bt<0><<<dim3(4, 24), 256, 0, stream>>>(slow_bf, Wih_bf, b_ih, gi, 256, 1536, 640);

  // distributed GRU scan — cooperative launch guarantees all 512 WGs co-resident;
  // fall back to a regular launch (512 <= 768-block capacity at 48 KB LDS) if unavailable.
  {
    const float* gi_c = gi;
    const unsigned short* whh_c = Whh_bf;
    const float* bhh_c = b_hh;
    unsigned long long* hall_c = Hall8;
    unsigned int* flags_c = flags;
    void* args[] = {(void*)&gi_c, (void*)&whh_c, (void*)&bhh_c, (void*)&hall_c, (void*)&flags_c};
    hipError_t err = hipLaunchCooperativeKernel((void*)gru_scan2, dim3(512), dim3(64), args, 0, stream);
    if (err != hipSuccess) {
      gru_scan2<<<512, 64, 0, stream>>>(gi, Whh_bf, b_hh, Hall8, flags);
    }
  }

  fc_scan<<<256, 256, 0, stream>>>(Hall, Wfc_bf, b_fc, z_ctx, out);
}

// Round 4
// 4844.288 us; speedup vs baseline: 1.6138x; 1.6138x over previous
//
#include <hip/hip_runtime.h>

// B=256, D=128, T=512, E=128, H=512, WH=512, WIN=64
typedef __attribute__((ext_vector_type(8))) short s8v;
typedef __attribute__((ext_vector_type(4))) float f4v;

#define MFMA16(a, b, c) __builtin_amdgcn_mfma_f32_16x16x32_bf16((a), (b), (c), 0, 0, 0)

__device__ __forceinline__ unsigned short f2bf(float f) {
  unsigned u = __float_as_uint(f);
  return (unsigned short)((u + 0x7fffu + ((u >> 16) & 1u)) >> 16);
}

// ---------- fp32 -> bf16 conversion (vectorized by 4) ----------
__global__ void cvt4_kernel(const float* __restrict__ in, unsigned short* __restrict__ out, int n4) {
  int i = blockIdx.x * blockDim.x + threadIdx.x;
  if (i >= n4) return;
  float4 v = ((const float4*)in)[i];
  ushort4 o;
  o.x = f2bf(v.x); o.y = f2bf(v.y); o.z = f2bf(v.z); o.w = f2bf(v.w);
  ((ushort4*)out)[i] = o;
}

// ---------- slow_input = [context | e] as bf16 (256 x 640) ----------
__global__ void build_slow_kernel(const float* __restrict__ context, const float* __restrict__ e,
                                  unsigned short* __restrict__ out) {
  int i = blockIdx.x * blockDim.x + threadIdx.x;
  if (i >= 256 * 640) return;
  int b = i / 640, c = i - b * 640;
  float v = (c < 512) ? context[b * 512 + c] : e[b * 128 + (c - 512)];
  out[i] = f2bf(v);
}

// ---------- generic GEMM: C[M][N] = act(A[M][K] @ B[N][K]^T + bias), bf16 in fp32 out ----------
template <int RELU>
__global__ __launch_bounds__(256) void gemm_bt(const unsigned short* __restrict__ A,
                                               const unsigned short* __restrict__ B,
                                               const float* __restrict__ bias, float* __restrict__ C,
                                               int M, int N, int K) {
  __shared__ unsigned short As[64][48];
  __shared__ unsigned short Bs[64][48];
  int tid = threadIdx.x;
  int lane = tid & 63, w = tid >> 6;
  int m = lane & 15, q = lane >> 4;
  int row0 = blockIdx.x * 64, col0 = blockIdx.y * 64;
  int sr = tid >> 2, sk = (tid & 3) * 8;
  const unsigned short* Ap = A + (size_t)(row0 + sr) * K + sk;
  const unsigned short* Bp = B + (size_t)(col0 + sr) * K + sk;
  f4v acc[4];
#pragma unroll
  for (int nt = 0; nt < 4; nt++) acc[nt] = (f4v){0.f, 0.f, 0.f, 0.f};

  for (int k0 = 0; k0 < K; k0 += 32) {
    *(uint4*)&As[sr][sk] = *(const uint4*)(Ap + k0);
    *(uint4*)&Bs[sr][sk] = *(const uint4*)(Bp + k0);
    __syncthreads();
    s8v a = *(const s8v*)&As[w * 16 + m][q * 8];
#pragma unroll
    for (int nt = 0; nt < 4; nt++) {
      s8v bb = *(const s8v*)&Bs[nt * 16 + m][q * 8];
      acc[nt] = MFMA16(a, bb, acc[nt]);
    }
    __syncthreads();
  }
#pragma unroll
  for (int nt = 0; nt < 4; nt++) {
    int c = col0 + nt * 16 + m;
    float bv = bias[c];
#pragma unroll
    for (int i = 0; i < 4; i++) {
      int r = row0 + w * 16 + q * 4 + i;
      float v = acc[nt][i] + bv;
      if (RELU) v = v > 0.f ? v : 0.f;
      C[(size_t)r * N + c] = v;
    }
  }
}

// ---------- phase C: distributed GRU scan, XCD-adaptive ----------
// 512 WGs x 64 threads = 16 batch-groups (16 rows) x 32 col-groups (16 h-cols).
// W_hh slice (48 rows x 512) LDS-resident as MFMA A-fragments.
//
// v4: fast path uses the SAME relaxed agent-scope atomics as the verified slow
// path (round-2 evidence: hand-rolled sc0 loads do NOT bypass L1 -> stale-L1
// poll deadlock; round-1 evidence: compiler agent-relaxed loads DO bypass L1,
// polls made progress before any acquire fence ran). The only fast-path
// difference: per-step cache-maintenance fences (buffer_wbl2/buffer_inv class)
// are dropped; with all 32 cgs of a bg placement-verified on ONE XCD, that
// XCD's L2 is the common serialization point. Producer orders h-stores before
// the flag store with s_waitcnt vmcnt(0) (store-ack at L2). Hedge: poll loop
// escalates to an acquire fence every 8192 failed spins -> if the no-fence
// model is wrong we degrade to ~round-1 speed, never to wrong answers.
// sync layout (u32): [0..511] xcdtab, [512] barA, [513] barB, [514] bad,
//                    flags at sync+1024: flags[bg*32+cg] (128B line per bg).
__global__ __launch_bounds__(64) void gru_scan4(const float* __restrict__ gi,
                                                const unsigned short* __restrict__ Whh,
                                                const float* __restrict__ bhh,
                                                unsigned long long* __restrict__ Hall8,
                                                unsigned int* __restrict__ sync) {
  __shared__ unsigned short wlds[3 * 16 * 64 * 8];  // 48 KB: [g][kc][lane][8]
  int tid = threadIdx.x;
  int bid = blockIdx.x;

  // ---- one-time placement discovery ----
  unsigned xcd = __builtin_amdgcn_s_getreg(6164) & 15u;  // hwreg(XCC_ID=20, off 0, size 4)
  if (tid == 0) {
    __hip_atomic_store(&sync[bid], xcd, __ATOMIC_RELAXED, __HIP_MEMORY_SCOPE_AGENT);
    __builtin_amdgcn_fence(__ATOMIC_RELEASE, "agent");
    __hip_atomic_fetch_add(&sync[512], 1u, __ATOMIC_RELEASE, __HIP_MEMORY_SCOPE_AGENT);
  }
  {
    long sp = 0;
    while (__hip_atomic_load(&sync[512], __ATOMIC_RELAXED, __HIP_MEMORY_SCOPE_AGENT) < 512u &&
           sp < 200000000L) ++sp;
  }
  __builtin_amdgcn_fence(__ATOMIC_ACQUIRE, "agent");

  int below = 0, total = 0;
  bool sane = (xcd < 8u);
  for (int j8 = 0; j8 < 8; ++j8) {
    int j = tid * 8 + j8;
    unsigned v = __hip_atomic_load(&sync[j], __ATOMIC_RELAXED, __HIP_MEMORY_SCOPE_AGENT);
    if (v >= 8u) sane = false;
    if (v == xcd) {
      total++;
      if (j < bid) below++;
    }
  }
#pragma unroll
  for (int off = 1; off < 64; off <<= 1) {
    below += __shfl_xor(below, off, 64);
    total += __shfl_xor(total, off, 64);
  }
  bool ok = (total == 64) && (__ballot(sane) == 0xffffffffffffffffULL);
  if (!ok && tid == 0)
    __hip_atomic_store(&sync[514], 1u, __ATOMIC_RELAXED, __HIP_MEMORY_SCOPE_AGENT);
  if (tid == 0) {
    __builtin_amdgcn_fence(__ATOMIC_RELEASE, "agent");
    __hip_atomic_fetch_add(&sync[513], 1u, __ATOMIC_RELEASE, __HIP_MEMORY_SCOPE_AGENT);
  }
  {
    long sp = 0;
    while (__hip_atomic_load(&sync[513], __ATOMIC_RELAXED, __HIP_MEMORY_SCOPE_AGENT) < 512u &&
           sp < 200000000L) ++sp;
  }
  __builtin_amdgcn_fence(__ATOMIC_ACQUIRE, "agent");
  bool fast = (__hip_atomic_load(&sync[514], __ATOMIC_RELAXED, __HIP_MEMORY_SCOPE_AGENT) == 0u);

  int bg, cg;
  if (fast) {
    bg = (int)xcd * 2 + (below >> 5);  // 2 bgs per XCD
    cg = below & 31;
  } else {
    bg = bid >> 5;
    cg = bid & 31;
  }
  int b0 = bg * 16;
  int n = tid & 15, q = tid >> 4;

  // stage W slice into LDS in A-fragment order (one-time, 48 KB)
#pragma unroll 1
  for (int it = 0; it < 48; ++it) {
    int g = it >> 4, kc = it & 15;
    int row = g * 512 + cg * 16 + n;
    int kcol = kc * 32 + q * 8;
    *(uint4*)&wlds[(it * 64 + tid) * 8] = *(const uint4*)(Whh + (size_t)row * 512 + kcol);
  }

  // time-invariant gate inputs (gi includes b_ih; fold b_hh for r,z; keep n-gate separate)
  float gir[4], giz[4], gin[4], bhn[4];
#pragma unroll
  for (int i = 0; i < 4; ++i) {
    int c = cg * 16 + q * 4 + i;
    const float* gp = gi + (size_t)(b0 + n) * 1536 + c;
    gir[i] = gp[0] + bhh[c];
    giz[i] = gp[512] + bhh[c + 512];
    gin[i] = gp[1024];
    bhn[i] = bhh[c + 1024];
  }
  float hp[4] = {0.f, 0.f, 0.f, 0.f};
  __syncthreads();

  unsigned int* flags = sync + 1024;
  unsigned int* myflag = flags + bg * 32 + cg;
  unsigned int* pollp = flags + bg * 32 + (tid & 31);
  size_t rowbase = (size_t)(b0 + n) * 512 * 128;  // 128 u64 per (b,t)
  size_t stoff = (size_t)cg * 4 + q;              // (cg*16+q*4)/4

  if (fast) {
    // ============ FAST PATH: XCD-local L2 exchange, no per-step cache fences ============
#pragma unroll 1
    for (int t = 0; t < 512; ++t) {
      f4v ar = {gir[0], gir[1], gir[2], gir[3]};
      f4v az = {giz[0], giz[1], giz[2], giz[3]};
      f4v an = {bhn[0], bhn[1], bhn[2], bhn[3]};
      if (t > 0) {
        unsigned tgt = (unsigned)t;
        for (long sp = 0; sp < 500000L; ++sp) {
          unsigned v = __hip_atomic_load(pollp, __ATOMIC_RELAXED, __HIP_MEMORY_SCOPE_AGENT);
          if (__ballot(v >= tgt) == 0xffffffffffffffffULL) break;
          // escalation hedge: if relaxed polls can't observe progress (L1 stale),
          // an acquire fence forces refetch; never triggers if the no-fence model holds
          if ((sp & 8191) == 8191) __builtin_amdgcn_fence(__ATOMIC_ACQUIRE, "agent");
        }
        asm volatile("" ::: "memory");  // keep h-loads below the poll at compiler level
        unsigned long long* hp8 = Hall8 + rowbase + (size_t)(t - 1) * 128 + q * 2;
        s8v bf[16];
#pragma unroll
        for (int kc = 0; kc < 16; ++kc) {
          union { unsigned long long u[2]; s8v v; } uv;
          uv.u[0] = __hip_atomic_load(hp8 + kc * 8, __ATOMIC_RELAXED, __HIP_MEMORY_SCOPE_AGENT);
          uv.u[1] = __hip_atomic_load(hp8 + kc * 8 + 1, __ATOMIC_RELAXED, __HIP_MEMORY_SCOPE_AGENT);
          bf[kc] = uv.v;
        }
#pragma unroll
        for (int kc = 0; kc < 16; ++kc) {
          s8v a0 = *(const s8v*)&wlds[((0 * 16 + kc) * 64 + tid) * 8];
          ar = MFMA16(a0, bf[kc], ar);
          s8v a1 = *(const s8v*)&wlds[((1 * 16 + kc) * 64 + tid) * 8];
          az = MFMA16(a1, bf[kc], az);
          s8v a2 = *(const s8v*)&wlds[((2 * 16 + kc) * 64 + tid) * 8];
          an = MFMA16(a2, bf[kc], an);
        }
      }
      union { unsigned short s[4]; unsigned long long u; } pk;
#pragma unroll
      for (int i = 0; i < 4; ++i) {
        float r = 1.f / (1.f + __expf(-ar[i]));
        float zg = 1.f / (1.f + __expf(-az[i]));
        float x = gin[i] + r * an[i];
        float ex = __expf(2.f * x);
        float nn = 1.f - 2.f / (ex + 1.f);
        float h = (1.f - zg) * nn + zg * hp[i];
        hp[i] = h;
        pk.s[i] = f2bf(h);
      }
      __hip_atomic_store(Hall8 + rowbase + (size_t)t * 128 + stoff, pk.u, __ATOMIC_RELAXED,
                         __HIP_MEMORY_SCOPE_AGENT);
      // order: h-stores acked at L2 before flag store (no cache-wide writeback needed)
      asm volatile("s_waitcnt vmcnt(0)" ::: "memory");
      if (tid == 0)
        __hip_atomic_store(myflag, (unsigned int)(t + 1), __ATOMIC_RELAXED,
                           __HIP_MEMORY_SCOPE_AGENT);
    }
  } else {
    // ================= SLOW PATH: verified agent-scope exchange =================
#pragma unroll 1
    for (int t = 0; t < 512; ++t) {
      f4v ar = {gir[0], gir[1], gir[2], gir[3]};
      f4v az = {giz[0], giz[1], giz[2], giz[3]};
      f4v an = {bhn[0], bhn[1], bhn[2], bhn[3]};
      if (t > 0) {
        unsigned int tgt = (unsigned int)t;
        for (long sp = 0; sp < 500000L; ++sp) {
          unsigned int v = __hip_atomic_load(pollp, __ATOMIC_RELAXED, __HIP_MEMORY_SCOPE_AGENT);
          if (__ballot(v >= tgt) == 0xffffffffffffffffULL) break;
        }
        __builtin_amdgcn_fence(__ATOMIC_ACQUIRE, "agent");
        unsigned long long* hp8 = Hall8 + rowbase + (size_t)(t - 1) * 128 + q * 2;
        s8v bf[16];
#pragma unroll
        for (int kc = 0; kc < 16; ++kc) {
          union { unsigned long long u[2]; s8v v; } uv;
          uv.u[0] = __hip_atomic_load(hp8 + kc * 8, __ATOMIC_RELAXED, __HIP_MEMORY_SCOPE_AGENT);
          uv.u[1] = __hip_atomic_load(hp8 + kc * 8 + 1, __ATOMIC_RELAXED, __HIP_MEMORY_SCOPE_AGENT);
          bf[kc] = uv.v;
        }
#pragma unroll
        for (int kc = 0; kc < 16; ++kc) {
          s8v a0 = *(const s8v*)&wlds[((0 * 16 + kc) * 64 + tid) * 8];
          ar = MFMA16(a0, bf[kc], ar);
          s8v a1 = *(const s8v*)&wlds[((1 * 16 + kc) * 64 + tid) * 8];
          az = MFMA16(a1, bf[kc], az);
          s8v a2 = *(const s8v*)&wlds[((2 * 16 + kc) * 64 + tid) * 8];
          an = MFMA16(a2, bf[kc], an);
        }
      }
      union { unsigned short s[4]; unsigned long long u; } pk;
#pragma unroll
      for (int i = 0; i < 4; ++i) {
        float r = 1.f / (1.f + __expf(-ar[i]));
        float zg = 1.f / (1.f + __expf(-az[i]));
        float x = gin[i] + r * an[i];
        float ex = __expf(2.f * x);
        float nn = 1.f - 2.f / (ex + 1.f);
        float h = (1.f - zg) * nn + zg * hp[i];
        hp[i] = h;
        pk.s[i] = f2bf(h);
      }
      __hip_atomic_store(Hall8 + rowbase + (size_t)t * 128 + stoff, pk.u, __ATOMIC_RELAXED,
                         __HIP_MEMORY_SCOPE_AGENT);
      __builtin_amdgcn_fence(__ATOMIC_RELEASE, "agent");
      if (tid == 0)
        __hip_atomic_store(myflag, (unsigned int)(t + 1), __ATOMIC_RELAXED,
                           __HIP_MEMORY_SCOPE_AGENT);
    }
  }
}

// ---------- phase D+E fused: inc = Hall @ Wfc^T + bfc; out[b,d,t] = zp0 + cumsum_t(inc) ----------
__global__ __launch_bounds__(256) void fc_scan(const unsigned short* __restrict__ Hall,
                                               const unsigned short* __restrict__ Wfc,
                                               const float* __restrict__ bfc,
                                               const float* __restrict__ zctx,
                                               float* __restrict__ out) {
  __shared__ unsigned short hs[16][520];
  int tid = threadIdx.x;
  int lane = tid & 63, w = tid >> 6;
  int m = lane & 15, q = lane >> 4;
  int b = blockIdx.x;

  s8v wf[2][16];
  float bf_r[2], carry[2];
#pragma unroll
  for (int j = 0; j < 2; j++) {
    int d = (2 * w + j) * 16 + m;
#pragma unroll
    for (int kc = 0; kc < 16; kc++)
      wf[j][kc] = *(const s8v*)(Wfc + (size_t)d * 512 + kc * 32 + q * 8);
    bf_r[j] = bfc[d];
    carry[j] = zctx[((size_t)b * 128 + d) * 64 + 63];
  }

#pragma unroll 1
  for (int chunk = 0; chunk < 32; chunk++) {
    int t0 = chunk * 16;
    {
      int mm = tid >> 4, ci = (tid & 15) * 4;
      const unsigned short* src = Hall + ((size_t)b * 512 + t0 + mm) * 512 + ci * 8;
#pragma unroll
      for (int o = 0; o < 4; o++) {
        uint4 v = *(const uint4*)(src + o * 8);
        *(uint4*)&hs[mm][(ci + o) * 8] = v;
      }
    }
    __syncthreads();
    s8v af[16];
#pragma unroll
    for (int kc = 0; kc < 16; kc++) af[kc] = *(const s8v*)&hs[m][kc * 32 + q * 8];
    f4v acc[2];
    acc[0] = (f4v){0.f, 0.f, 0.f, 0.f};
    acc[1] = (f4v){0.f, 0.f, 0.f, 0.f};
#pragma unroll
    for (int kc = 0; kc < 16; kc++) {
      acc[0] = MFMA16(af[kc], wf[0][kc], acc[0]);
      acc[1] = MFMA16(af[kc], wf[1][kc], acc[1]);
    }
    __syncthreads();

#pragma unroll
    for (int j = 0; j < 2; j++) {
      float s0 = acc[j][0] + bf_r[j];
      float s1 = s0 + acc[j][1] + bf_r[j];
      float s2 = s1 + acc[j][2] + bf_r[j];
      float s3 = s2 + acc[j][3] + bf_r[j];
      float tot = s3;
      float incl = tot;
      float u = __shfl_up(incl, 16, 64);
      if (q >= 1) incl += u;
      u = __shfl_up(incl, 32, 64);
      if (q >= 2) incl += u;
      float excl = incl - tot;
      float add = excl + carry[j];
      int d = (2 * w + j) * 16 + m;
      float4 o4 = make_float4(s0 + add, s1 + add, s2 + add, s3 + add);
      *(float4*)(out + ((size_t)b * 128 + d) * 512 + t0 + q * 4) = o4;
      float chunktot = __shfl(incl, 48 + m, 64);
      carry[j] += chunktot;
    }
  }
}

extern "C" void kernel_launch(void* const* d_in, const int* in_sizes, int n_in,
                              void* d_out, int out_size, void* d_ws, size_t ws_size,
                              hipStream_t stream) {
  const float* z_ctx = (const float*)d_in[0];
  const float* e     = (const float*)d_in[4];
  const float* W_enc = (const float*)d_in[5];
  const float* b_enc = (const float*)d_in[6];
  const float* W_ih  = (const float*)d_in[7];
  const float* W_hh  = (const float*)d_in[8];
  const float* b_ih  = (const float*)d_in[9];
  const float* b_hh  = (const float*)d_in[10];
  const float* W_fc  = (const float*)d_in[11];
  const float* b_fc  = (const float*)d_in[12];
  float* out = (float*)d_out;

  char* ws = (char*)d_ws;
  const size_t OFF_WENC = 0;          // 512*8192*2
  const size_t OFF_ZCTX = 8388608;    // 256*8192*2
  const size_t OFF_WIH  = 12582912;   // 1536*640*2
  const size_t OFF_WHH  = 14548992;   // 1536*512*2
  const size_t OFF_WFC  = 16121856;   // 128*512*2
  const size_t OFF_CTX  = 16252928;   // 256*512*4
  const size_t OFF_SLOW = 16777216;   // 256*640*2
  const size_t OFF_GI   = 17104896;   // 256*1536*4
  const size_t OFF_HALL = 18677760;   // 256*512*512*2
  const size_t OFF_SYNC = OFF_HALL + 134217728ull;  // xcdtab+bars+flags (32KB reserved)
  const size_t NEED = OFF_SYNC + 32768;
  if (ws_size < NEED) return;

  unsigned short* Wenc_bf = (unsigned short*)(ws + OFF_WENC);
  unsigned short* zctx_bf = (unsigned short*)(ws + OFF_ZCTX);
  unsigned short* Wih_bf  = (unsigned short*)(ws + OFF_WIH);
  unsigned short* Whh_bf  = (unsigned short*)(ws + OFF_WHH);
  unsigned short* Wfc_bf  = (unsigned short*)(ws + OFF_WFC);
  float* context          = (float*)(ws + OFF_CTX);
  unsigned short* slow_bf = (unsigned short*)(ws + OFF_SLOW);
  float* gi               = (float*)(ws + OFF_GI);
  unsigned short* Hall    = (unsigned short*)(ws + OFF_HALL);
  unsigned long long* Hall8 = (unsigned long long*)(ws + OFF_HALL);
  unsigned int* sync      = (unsigned int*)(ws + OFF_SYNC);

  hipMemsetAsync(sync, 0, 8192, stream);

  cvt4_kernel<<<4096, 256, 0, stream>>>(W_enc, Wenc_bf, 512 * 8192 / 4);
  cvt4_kernel<<<2048, 256, 0, stream>>>(z_ctx, zctx_bf, 256 * 8192 / 4);
  cvt4_kernel<<<960, 256, 0, stream>>>(W_ih, Wih_bf, 1536 * 640 / 4);
  cvt4_kernel<<<768, 256, 0, stream>>>(W_hh, Whh_bf, 1536 * 512 / 4);
  cvt4_kernel<<<64, 256, 0, stream>>>(W_fc, Wfc_bf, 128 * 512 / 4);

  gemm_bt<1><<<dim3(4, 8), 256, 0, stream>>>(zctx_bf, Wenc_bf, b_enc, context, 256, 512, 8192);
  build_slow_kernel<<<640, 256, 0, stream>>>(context, e, slow_bf);
  gemm_bt<0><<<dim3(4, 24), 256, 0, stream>>>(slow_bf, Wih_bf, b_ih, gi, 256, 1536, 640);

  // distributed GRU scan — cooperative launch guarantees all 512 WGs co-resident;
  // fall back to a regular launch (512 <= 768-block capacity at 48 KB LDS) if unavailable.
  {
    const float* gi_c = gi;
    const unsigned short* whh_c = Whh_bf;
    const float* bhh_c = b_hh;
    unsigned long long* hall_c = Hall8;
    unsigned int* sync_c = sync;
    void* args[] = {(void*)&gi_c, (void*)&whh_c, (void*)&bhh_c, (void*)&hall_c, (void*)&sync_c};
    hipError_t err = hipLaunchCooperativeKernel((void*)gru_scan4, dim3(512), dim3(64), args, 0, stream);
    if (err != hipSuccess) {
      gru_scan4<<<512, 64, 0, stream>>>(gi, Whh_bf, b_hh, Hall8, sync);
    }
  }

  fc_scan<<<256, 256, 0, stream>>>(Hall, Wfc_bf, b_fc, z_ctx, out);
}

// Round 5
// 2496.504 us; speedup vs baseline: 3.1315x; 1.9404x over previous
//
#include <hip/hip_runtime.h>

// B=256, D=128, T=512, E=128, H=512, WH=512, WIN=64
typedef __attribute__((ext_vector_type(8))) short s8v;
typedef __attribute__((ext_vector_type(4))) float f4v;

#define MFMA16(a, b, c) __builtin_amdgcn_mfma_f32_16x16x32_bf16((a), (b), (c), 0, 0, 0)

__device__ __forceinline__ unsigned short f2bf(float f) {
  unsigned u = __float_as_uint(f);
  return (unsigned short)((u + 0x7fffu + ((u >> 16) & 1u)) >> 16);
}

// ---------- fp32 -> bf16 conversion (vectorized by 4) ----------
__global__ void cvt4_kernel(const float* __restrict__ in, unsigned short* __restrict__ out, int n4) {
  int i = blockIdx.x * blockDim.x + threadIdx.x;
  if (i >= n4) return;
  float4 v = ((const float4*)in)[i];
  ushort4 o;
  o.x = f2bf(v.x); o.y = f2bf(v.y); o.z = f2bf(v.z); o.w = f2bf(v.w);
  ((ushort4*)out)[i] = o;
}

// ---------- slow_input = [context | e] as bf16 (256 x 640) ----------
__global__ void build_slow_kernel(const float* __restrict__ context, const float* __restrict__ e,
                                  unsigned short* __restrict__ out) {
  int i = blockIdx.x * blockDim.x + threadIdx.x;
  if (i >= 256 * 640) return;
  int b = i / 640, c = i - b * 640;
  float v = (c < 512) ? context[b * 512 + c] : e[b * 128 + (c - 512)];
  out[i] = f2bf(v);
}

// ---------- generic GEMM: C[M][N] = act(A[M][K] @ B[N][K]^T + bias), bf16 in fp32 out ----------
template <int RELU>
__global__ __launch_bounds__(256) void gemm_bt(const unsigned short* __restrict__ A,
                                               const unsigned short* __restrict__ B,
                                               const float* __restrict__ bias, float* __restrict__ C,
                                               int M, int N, int K) {
  __shared__ unsigned short As[64][48];
  __shared__ unsigned short Bs[64][48];
  int tid = threadIdx.x;
  int lane = tid & 63, w = tid >> 6;
  int m = lane & 15, q = lane >> 4;
  int row0 = blockIdx.x * 64, col0 = blockIdx.y * 64;
  int sr = tid >> 2, sk = (tid & 3) * 8;
  const unsigned short* Ap = A + (size_t)(row0 + sr) * K + sk;
  const unsigned short* Bp = B + (size_t)(col0 + sr) * K + sk;
  f4v acc[4];
#pragma unroll
  for (int nt = 0; nt < 4; nt++) acc[nt] = (f4v){0.f, 0.f, 0.f, 0.f};

  for (int k0 = 0; k0 < K; k0 += 32) {
    *(uint4*)&As[sr][sk] = *(const uint4*)(Ap + k0);
    *(uint4*)&Bs[sr][sk] = *(const uint4*)(Bp + k0);
    __syncthreads();
    s8v a = *(const s8v*)&As[w * 16 + m][q * 8];
#pragma unroll
    for (int nt = 0; nt < 4; nt++) {
      s8v bb = *(const s8v*)&Bs[nt * 16 + m][q * 8];
      acc[nt] = MFMA16(a, bb, acc[nt]);
    }
    __syncthreads();
  }
#pragma unroll
  for (int nt = 0; nt < 4; nt++) {
    int c = col0 + nt * 16 + m;
    float bv = bias[c];
#pragma unroll
    for (int i = 0; i < 4; i++) {
      int r = row0 + w * 16 + q * 4 + i;
      float v = acc[nt][i] + bv;
      if (RELU) v = v > 0.f ? v : 0.f;
      C[(size_t)r * N + c] = v;
    }
  }
}

// ---------- phase C: distributed GRU scan, v5 ----------
// Geometry: 256 WGs x 64 threads = 16 batch-groups (16 rows) x 16 col-groups
// (32 h-cols each). W_hh slice = 96 rows x 512 = 96 KB LDS as MFMA A-frags
// -> 1 WG/CU, 256 CUs, trivially co-resident.
// Rationale (round-4 counters): exchange ops are agent-scope atomics serviced
// at the MALL regardless of XCD placement (FETCH 566->80 MB when per-step
// fences were dropped; latency stayed MALL-class). Dominant remaining cost is
// MALL request contention from broadcast fan-out; halving participants
// (32->16 cgs) halves h-read traffic (8->4 MB/step), flag producers, and the
// poll storm (512->256 WGs). Exchange protocol identical to verified round-4
// fast path: relaxed agent atomics, vmcnt(0) store-ack ordering before flag,
// escalation acquire fence every 8192 failed spins (never fired in round 4).
// flags[bg*32 + cg] (cg<16), one 128B line per bg.
__global__ __launch_bounds__(64) void gru_scan5(const float* __restrict__ gi,
                                                const unsigned short* __restrict__ Whh,
                                                const float* __restrict__ bhh,
                                                unsigned long long* __restrict__ Hall8,
                                                unsigned int* __restrict__ flags) {
  __shared__ unsigned short wlds[6 * 16 * 64 * 8];  // 96 KB: [gc=g*2+ct][kc][lane][8]
  int tid = threadIdx.x;
  int bid = blockIdx.x;
  int bg = bid >> 4, cg = bid & 15;
  int b0 = bg * 16;
  int n = tid & 15, q = tid >> 4;

  // stage W slice into LDS in A-fragment order (one-time, 96 KB)
#pragma unroll 1
  for (int it = 0; it < 96; ++it) {
    int g = it >> 5, rem = it & 31, ct = rem >> 4, kc = rem & 15;
    int row = g * 512 + cg * 32 + ct * 16 + n;
    int kcol = kc * 32 + q * 8;
    *(uint4*)&wlds[(((g * 2 + ct) * 16 + kc) * 64 + tid) * 8] =
        *(const uint4*)(Whh + (size_t)row * 512 + kcol);
  }

  // time-invariant gate inputs (gi includes b_ih; fold b_hh for r,z; keep n-gate separate)
  float gir[2][4], giz[2][4], gin[2][4], bhn[2][4];
#pragma unroll
  for (int ct = 0; ct < 2; ++ct) {
#pragma unroll
    for (int i = 0; i < 4; ++i) {
      int c = cg * 32 + ct * 16 + q * 4 + i;
      const float* gp = gi + (size_t)(b0 + n) * 1536 + c;
      gir[ct][i] = gp[0] + bhh[c];
      giz[ct][i] = gp[512] + bhh[c + 512];
      gin[ct][i] = gp[1024];
      bhn[ct][i] = bhh[c + 1024];
    }
  }
  float hp[2][4] = {{0.f, 0.f, 0.f, 0.f}, {0.f, 0.f, 0.f, 0.f}};
  __syncthreads();

  unsigned int* myflag = flags + bg * 32 + cg;
  const unsigned int* pollp = flags + bg * 32 + (tid & 15);
  size_t rowbase = (size_t)(b0 + n) * 512 * 128;  // 128 u64 per (b,t)

#pragma unroll 1
  for (int t = 0; t < 512; ++t) {
    f4v ar[2], az[2], an[2];
#pragma unroll
    for (int ct = 0; ct < 2; ++ct) {
      ar[ct] = (f4v){gir[ct][0], gir[ct][1], gir[ct][2], gir[ct][3]};
      az[ct] = (f4v){giz[ct][0], giz[ct][1], giz[ct][2], giz[ct][3]};
      an[ct] = (f4v){bhn[ct][0], bhn[ct][1], bhn[ct][2], bhn[ct][3]};
    }
    if (t > 0) {
      unsigned tgt = (unsigned)t;
      for (long sp = 0; sp < 500000L; ++sp) {
        unsigned v = __hip_atomic_load(pollp, __ATOMIC_RELAXED, __HIP_MEMORY_SCOPE_AGENT);
        if (__ballot(v >= tgt) == 0xffffffffffffffffULL) break;
        // escalation hedge: never fired in round 4; kept as correctness insurance
        if ((sp & 8191) == 8191) __builtin_amdgcn_fence(__ATOMIC_ACQUIRE, "agent");
      }
      asm volatile("" ::: "memory");  // keep h-loads below the poll at compiler level
      unsigned long long* hp8 = Hall8 + rowbase + (size_t)(t - 1) * 128 + q * 2;
      s8v bf[16];
#pragma unroll
      for (int kc = 0; kc < 16; ++kc) {
        union { unsigned long long u[2]; s8v v; } uv;
        uv.u[0] = __hip_atomic_load(hp8 + kc * 8, __ATOMIC_RELAXED, __HIP_MEMORY_SCOPE_AGENT);
        uv.u[1] = __hip_atomic_load(hp8 + kc * 8 + 1, __ATOMIC_RELAXED, __HIP_MEMORY_SCOPE_AGENT);
        bf[kc] = uv.v;
      }
#pragma unroll
      for (int kc = 0; kc < 16; ++kc) {
#pragma unroll
        for (int ct = 0; ct < 2; ++ct) {
          s8v a0 = *(const s8v*)&wlds[(((0 + ct) * 16 + kc) * 64 + tid) * 8];
          ar[ct] = MFMA16(a0, bf[kc], ar[ct]);
          s8v a1 = *(const s8v*)&wlds[(((2 + ct) * 16 + kc) * 64 + tid) * 8];
          az[ct] = MFMA16(a1, bf[kc], az[ct]);
          s8v a2 = *(const s8v*)&wlds[(((4 + ct) * 16 + kc) * 64 + tid) * 8];
          an[ct] = MFMA16(a2, bf[kc], an[ct]);
        }
      }
    }
#pragma unroll
    for (int ct = 0; ct < 2; ++ct) {
      union { unsigned short s[4]; unsigned long long u; } pk;
#pragma unroll
      for (int i = 0; i < 4; ++i) {
        float r = 1.f / (1.f + __expf(-ar[ct][i]));
        float zg = 1.f / (1.f + __expf(-az[ct][i]));
        float x = gin[ct][i] + r * an[ct][i];
        float ex = __expf(2.f * x);
        float nn = 1.f - 2.f / (ex + 1.f);
        float h = (1.f - zg) * nn + zg * hp[ct][i];
        hp[ct][i] = h;
        pk.s[i] = f2bf(h);
      }
      __hip_atomic_store(Hall8 + rowbase + (size_t)t * 128 + (size_t)(cg * 8 + ct * 4 + q), pk.u,
                         __ATOMIC_RELAXED, __HIP_MEMORY_SCOPE_AGENT);
    }
    // order: both h-stores acked at the coherence point before flag store
    asm volatile("s_waitcnt vmcnt(0)" ::: "memory");
    if (tid == 0)
      __hip_atomic_store(myflag, (unsigned int)(t + 1), __ATOMIC_RELAXED,
                         __HIP_MEMORY_SCOPE_AGENT);
  }
}

// ---------- phase D+E fused: inc = Hall @ Wfc^T + bfc; out[b,d,t] = zp0 + cumsum_t(inc) ----------
__global__ __launch_bounds__(256) void fc_scan(const unsigned short* __restrict__ Hall,
                                               const unsigned short* __restrict__ Wfc,
                                               const float* __restrict__ bfc,
                                               const float* __restrict__ zctx,
                                               float* __restrict__ out) {
  __shared__ unsigned short hs[16][520];
  int tid = threadIdx.x;
  int lane = tid & 63, w = tid >> 6;
  int m = lane & 15, q = lane >> 4;
  int b = blockIdx.x;

  s8v wf[2][16];
  float bf_r[2], carry[2];
#pragma unroll
  for (int j = 0; j < 2; j++) {
    int d = (2 * w + j) * 16 + m;
#pragma unroll
    for (int kc = 0; kc < 16; kc++)
      wf[j][kc] = *(const s8v*)(Wfc + (size_t)d * 512 + kc * 32 + q * 8);
    bf_r[j] = bfc[d];
    carry[j] = zctx[((size_t)b * 128 + d) * 64 + 63];
  }

#pragma unroll 1
  for (int chunk = 0; chunk < 32; chunk++) {
    int t0 = chunk * 16;
    {
      int mm = tid >> 4, ci = (tid & 15) * 4;
      const unsigned short* src = Hall + ((size_t)b * 512 + t0 + mm) * 512 + ci * 8;
#pragma unroll
      for (int o = 0; o < 4; o++) {
        uint4 v = *(const uint4*)(src + o * 8);
        *(uint4*)&hs[mm][(ci + o) * 8] = v;
      }
    }
    __syncthreads();
    s8v af[16];
#pragma unroll
    for (int kc = 0; kc < 16; kc++) af[kc] = *(const s8v*)&hs[m][kc * 32 + q * 8];
    f4v acc[2];
    acc[0] = (f4v){0.f, 0.f, 0.f, 0.f};
    acc[1] = (f4v){0.f, 0.f, 0.f, 0.f};
#pragma unroll
    for (int kc = 0; kc < 16; kc++) {
      acc[0] = MFMA16(af[kc], wf[0][kc], acc[0]);
      acc[1] = MFMA16(af[kc], wf[1][kc], acc[1]);
    }
    __syncthreads();

#pragma unroll
    for (int j = 0; j < 2; j++) {
      float s0 = acc[j][0] + bf_r[j];
      float s1 = s0 + acc[j][1] + bf_r[j];
      float s2 = s1 + acc[j][2] + bf_r[j];
      float s3 = s2 + acc[j][3] + bf_r[j];
      float tot = s3;
      float incl = tot;
      float u = __shfl_up(incl, 16, 64);
      if (q >= 1) incl += u;
      u = __shfl_up(incl, 32, 64);
      if (q >= 2) incl += u;
      float excl = incl - tot;
      float add = excl + carry[j];
      int d = (2 * w + j) * 16 + m;
      float4 o4 = make_float4(s0 + add, s1 + add, s2 + add, s3 + add);
      *(float4*)(out + ((size_t)b * 128 + d) * 512 + t0 + q * 4) = o4;
      float chunktot = __shfl(incl, 48 + m, 64);
      carry[j] += chunktot;
    }
  }
}

extern "C" void kernel_launch(void* const* d_in, const int* in_sizes, int n_in,
                              void* d_out, int out_size, void* d_ws, size_t ws_size,
                              hipStream_t stream) {
  const float* z_ctx = (const float*)d_in[0];
  const float* e     = (const float*)d_in[4];
  const float* W_enc = (const float*)d_in[5];
  const float* b_enc = (const float*)d_in[6];
  const float* W_ih  = (const float*)d_in[7];
  const float* W_hh  = (const float*)d_in[8];
  const float* b_ih  = (const float*)d_in[9];
  const float* b_hh  = (const float*)d_in[10];
  const float* W_fc  = (const float*)d_in[11];
  const float* b_fc  = (const float*)d_in[12];
  float* out = (float*)d_out;

  char* ws = (char*)d_ws;
  const size_t OFF_WENC = 0;          // 512*8192*2
  const size_t OFF_ZCTX = 8388608;    // 256*8192*2
  const size_t OFF_WIH  = 12582912;   // 1536*640*2
  const size_t OFF_WHH  = 14548992;   // 1536*512*2
  const size_t OFF_WFC  = 16121856;   // 128*512*2
  const size_t OFF_CTX  = 16252928;   // 256*512*4
  const size_t OFF_SLOW = 16777216;   // 256*640*2
  const size_t OFF_GI   = 17104896;   // 256*1536*4
  const size_t OFF_HALL = 18677760;   // 256*512*512*2
  const size_t OFF_SYNC = OFF_HALL + 134217728ull;  // flags: 16*32*4 = 2048 (32KB reserved)
  const size_t NEED = OFF_SYNC + 32768;
  if (ws_size < NEED) return;

  unsigned short* Wenc_bf = (unsigned short*)(ws + OFF_WENC);
  unsigned short* zctx_bf = (unsigned short*)(ws + OFF_ZCTX);
  unsigned short* Wih_bf  = (unsigned short*)(ws + OFF_WIH);
  unsigned short* Whh_bf  = (unsigned short*)(ws + OFF_WHH);
  unsigned short* Wfc_bf  = (unsigned short*)(ws + OFF_WFC);
  float* context          = (float*)(ws + OFF_CTX);
  unsigned short* slow_bf = (unsigned short*)(ws + OFF_SLOW);
  float* gi               = (float*)(ws + OFF_GI);
  unsigned short* Hall    = (unsigned short*)(ws + OFF_HALL);
  unsigned long long* Hall8 = (unsigned long long*)(ws + OFF_HALL);
  unsigned int* flags     = (unsigned int*)(ws + OFF_SYNC);

  hipMemsetAsync(flags, 0, 4096, stream);

  cvt4_kernel<<<4096, 256, 0, stream>>>(W_enc, Wenc_bf, 512 * 8192 / 4);
  cvt4_kernel<<<2048, 256, 0, stream>>>(z_ctx, zctx_bf, 256 * 8192 / 4);
  cvt4_kernel<<<960, 256, 0, stream>>>(W_ih, Wih_bf, 1536 * 640 / 4);
  cvt4_kernel<<<768, 256, 0, stream>>>(W_hh, Whh_bf, 1536 * 512 / 4);
  cvt4_kernel<<<64, 256, 0, stream>>>(W_fc, Wfc_bf, 128 * 512 / 4);

  gemm_bt<1><<<dim3(4, 8), 256, 0, stream>>>(zctx_bf, Wenc_bf, b_enc, context, 256, 512, 8192);
  build_slow_kernel<<<640, 256, 0, stream>>>(context, e, slow_bf);
  gemm_bt<0><<<dim3(4, 24), 256, 0, stream>>>(slow_bf, Wih_bf, b_ih, gi, 256, 1536, 640);

  // distributed GRU scan — 256 WGs at 96 KB LDS = 1 WG/CU, co-resident by
  // construction; cooperative launch preferred, regular launch equivalent.
  {
    const float* gi_c = gi;
    const unsigned short* whh_c = Whh_bf;
    const float* bhh_c = b_hh;
    unsigned long long* hall_c = Hall8;
    unsigned int* flags_c = flags;
    void* args[] = {(void*)&gi_c, (void*)&whh_c, (void*)&bhh_c, (void*)&hall_c, (void*)&flags_c};
    hipError_t err = hipLaunchCooperativeKernel((void*)gru_scan5, dim3(256), dim3(64), args, 0, stream);
    if (err != hipSuccess) {
      gru_scan5<<<256, 64, 0, stream>>>(gi, Whh_bf, b_hh, Hall8, flags);
    }
  }

  fc_scan<<<256, 256, 0, stream>>>(Hall, Wfc_bf, b_fc, z_ctx, out);
}